// Round 3
// baseline (140.982 us; speedup 1.0000x reference)
//
#include <hip/hip_runtime.h>
#include <hip/hip_bf16.h>
#include <float.h>
#include <limits.h>

#define FEAT       256
#define GAMMA_F    0.1f
#define EPS_F      1e-8f
#define KSEL       64        // BUDGET
#define NBUCK      8192      // 13-bit histogram of flipped-float keys
#define CAP        4096      // compaction capacity (expected ~90 used)
#define NB2        64        // select_kernel blocks

// Monotonic float -> uint transform (ascending order preserved).
__device__ __forceinline__ unsigned key_of(float v) {
    unsigned u = __float_as_uint(v);
    return u ^ ((u >> 31) ? 0xFFFFFFFFu : 0x80000000u);
}

__device__ __forceinline__ bool comes_first(float va, int ia, float vb, int ib) {
    return (va > vb) || (va == vb && ia < ib);
}

// ---------------------------------------------------------------------------
// Kernel 1: fused edge-score + histogram. One 64-lane wave per candidate;
// lane i loads float4 of the candidate row and injected_feat, wave-reduces
// dot and squared norms via shfl_xor; lane 0 writes the score AND bumps the
// global histogram bucket (score is still in-register -> no re-read pass).
// ---------------------------------------------------------------------------
__global__ __launch_bounds__(256) void edge_score_kernel(
    const float* __restrict__ infl,
    const float* __restrict__ feats,
    const int*   __restrict__ cand,
    const float* __restrict__ inj,
    float*       __restrict__ scores,   // d_out + KSEL
    unsigned*    __restrict__ hist,
    int num_cand)
{
    const int gtid = blockIdx.x * blockDim.x + threadIdx.x;
    const int wave = gtid >> 6;
    const int lane = threadIdx.x & 63;
    if (wave >= num_cand) return;

    const int row = cand[wave];
    const float4 f = *reinterpret_cast<const float4*>(
        feats + (size_t)row * FEAT + lane * 4);
    const float4 g = *reinterpret_cast<const float4*>(inj + lane * 4);

    float dot = f.x * g.x + f.y * g.y + f.z * g.z + f.w * g.w;
    float nf  = f.x * f.x + f.y * f.y + f.z * f.z + f.w * f.w;
    float ng  = g.x * g.x + g.y * g.y + g.z * g.z + g.w * g.w;

    #pragma unroll
    for (int off = 32; off > 0; off >>= 1) {
        dot += __shfl_xor(dot, off);
        nf  += __shfl_xor(nf, off);
        ng  += __shfl_xor(ng, off);
    }

    if (lane == 0) {
        const float denom = fmaxf(sqrtf(nf), EPS_F) * fmaxf(sqrtf(ng), EPS_F);
        const float s = infl[wave] - GAMMA_F * (dot / denom);
        scores[wave] = s;
        atomicAdd(&hist[key_of(s) >> 19], 1u);
    }
}

// ---------------------------------------------------------------------------
// Kernel 2: fused select. Each block redundantly computes threshold bucket B
// (suffix-scan of the L2-hot 32 KB histogram), grid-strides the compaction of
// survivors (bucket >= B), then the LAST block to finish (device-scope ticket,
// no dispatch-order assumption) bitonic-sorts the ~90 survivors and writes
// the exact top-64 node indices.
// ---------------------------------------------------------------------------
__global__ __launch_bounds__(256) void select_kernel(
    const float*    __restrict__ scores,
    const unsigned* __restrict__ hist,
    unsigned*       __restrict__ cnt,
    unsigned*       __restrict__ done,
    float*          __restrict__ ws_v,
    int*            __restrict__ ws_i,
    const int*      __restrict__ cand,
    float*          __restrict__ out,   // d_out[0..KSEL)
    int n)
{
    __shared__ unsigned csum[256];
    __shared__ unsigned sB;
    __shared__ int      sLast;
    __shared__ float    sv[CAP];
    __shared__ int      si[CAP];

    const int t = threadIdx.x;

    // --- 1. threshold bucket B (computed redundantly per block) ---
    {
        const int hi = NBUCK - 32 * t;     // chunk t = buckets [hi-32, hi)
        unsigned s = 0;
        for (int b = hi - 32; b < hi; ++b) s += hist[b];
        csum[t] = s;
    }
    __syncthreads();
    if (t == 0) {
        unsigned cum = 0;
        int tc = 0;
        for (; tc < 256; ++tc) {
            if (cum + csum[tc] >= KSEL) break;
            cum += csum[tc];
        }
        unsigned B = 0;
        if (tc < 256) {
            int b = NBUCK - 32 * tc - 1;
            for (int k = 0; k < 32; ++k, --b) {
                cum += hist[b];
                if (cum >= KSEL) { B = (unsigned)b; break; }
            }
        }
        sB = B;
    }
    __syncthreads();
    const unsigned B = sB;

    // --- 2. compact survivors (grid-stride) ---
    for (int i = blockIdx.x * 256 + t; i < n; i += NB2 * 256) {
        const float v = scores[i];
        if ((key_of(v) >> 19) >= B) {
            const unsigned p = atomicAdd(cnt, 1u);
            if (p < CAP) { ws_v[p] = v; ws_i[p] = i; }
        }
    }

    // --- 3. last-finished block does the final top-64 ---
    __threadfence();            // publish ws_v/ws_i before the ticket
    __syncthreads();
    if (t == 0) sLast = (atomicAdd(done, 1u) == (unsigned)(NB2 - 1));
    __syncthreads();
    if (!sLast) return;
    __threadfence();            // acquire other blocks' ws_v/ws_i writes

    const int m = (int)min(atomicAdd(cnt, 0u), (unsigned)CAP);

    if (m <= 256) {
        // bitonic sort of 256 slots: value desc, index asc (lax.top_k order)
        sv[t] = (t < m) ? ws_v[t] : -INFINITY;
        si[t] = (t < m) ? ws_i[t] : INT_MAX;
        __syncthreads();
        for (int k = 2; k <= 256; k <<= 1) {
            for (int j = k >> 1; j > 0; j >>= 1) {
                const int p = t ^ j;
                if (p > t) {
                    const float va = sv[t], vb = sv[p];
                    const int   ia = si[t], ib = si[p];
                    const bool asc = ((t & k) == 0);
                    const bool doSwap = asc ? comes_first(vb, ib, va, ia)
                                            : comes_first(va, ia, vb, ib);
                    if (doSwap) { sv[t] = vb; si[t] = ib; sv[p] = va; si[p] = ia; }
                }
                __syncthreads();
            }
        }
        if (t < KSEL) out[t] = (float)cand[si[t]];
        return;
    }

    // Fallback (never expected): serial argmax over m <= CAP survivors.
    __shared__ float wv[4];
    __shared__ int   wbi[4], wbs[4];
    for (int i = t; i < CAP; i += 256) {
        sv[i] = (i < m) ? ws_v[i] : -INFINITY;
        si[i] = (i < m) ? ws_i[i] : INT_MAX;
    }
    __syncthreads();
    for (int k = 0; k < KSEL; ++k) {
        float bv = -INFINITY; int bi = INT_MAX; int bs = 0;
        for (int i = t; i < CAP; i += 256) {
            if (comes_first(sv[i], si[i], bv, bi)) { bv = sv[i]; bi = si[i]; bs = i; }
        }
        #pragma unroll
        for (int off = 32; off > 0; off >>= 1) {
            const float ov = __shfl_xor(bv, off);
            const int   oi = __shfl_xor(bi, off);
            const int   os = __shfl_xor(bs, off);
            if (comes_first(ov, oi, bv, bi)) { bv = ov; bi = oi; bs = os; }
        }
        const int w = t >> 6;
        if ((t & 63) == 0) { wv[w] = bv; wbi[w] = bi; wbs[w] = bs; }
        __syncthreads();
        if (t == 0) {
            float fv = wv[0]; int fi = wbi[0]; int fs = wbs[0];
            #pragma unroll
            for (int j = 1; j < 4; ++j)
                if (comes_first(wv[j], wbi[j], fv, fi)) { fv = wv[j]; fi = wbi[j]; fs = wbs[j]; }
            out[k] = (float)cand[fi];
            sv[fs] = -INFINITY;
            si[fs] = INT_MAX;
        }
        __syncthreads();
    }
}

extern "C" void kernel_launch(void* const* d_in, const int* in_sizes, int n_in,
                              void* d_out, int out_size, void* d_ws, size_t ws_size,
                              hipStream_t stream) {
    const float* infl  = (const float*)d_in[0];   // [num_cand]
    const float* feats = (const float*)d_in[1];   // [num_nodes, 256]
    const int*   cand  = (const int*)d_in[2];     // [num_cand]
    const float* inj   = (const float*)d_in[3];   // [256]

    const int num_cand = in_sizes[0];

    float* out    = (float*)d_out;          // [0..64): indices-as-f32
    float* scores = (float*)d_out + KSEL;   // [64..64+num_cand): edge scores

    unsigned* ws_hist = (unsigned*)d_ws;              // NBUCK
    unsigned* ws_cnt  = ws_hist + NBUCK;              // 1
    unsigned* ws_done = ws_cnt + 1;                   // 1
    float*    ws_v    = (float*)(ws_done + 1);        // CAP
    int*      ws_i    = (int*)(ws_v + CAP);           // CAP

    // Zero histogram + counters (harness does not re-poison between replays).
    hipMemsetAsync(ws_hist, 0, (NBUCK + 2) * sizeof(unsigned), stream);

    // 1. Fused edge scores + histogram: one wave per candidate.
    {
        const int blocks = (num_cand + 3) / 4;
        edge_score_kernel<<<blocks, 256, 0, stream>>>(
            infl, feats, cand, inj, scores, ws_hist, num_cand);
    }

    // 2. Fused threshold + compact + final top-64.
    select_kernel<<<NB2, 256, 0, stream>>>(
        scores, ws_hist, ws_cnt, ws_done, ws_v, ws_i, cand, out, num_cand);
}

// Round 4
// 50.971 us; speedup vs baseline: 2.7659x; 2.7659x over previous
//
#include <hip/hip_runtime.h>
#include <hip/hip_bf16.h>
#include <float.h>
#include <limits.h>

#define FEAT       256
#define GAMMA_F    0.1f
#define EPS_F      1e-8f
#define KSEL       64        // BUDGET
#define NBUCK      8192      // 13-bit histogram of flipped-float keys
#define CAP        4096      // compaction capacity (expected ~90 used)
#define NB2        64        // select_kernel blocks
#define CPW        4         // candidates per wave (ILP in score kernel)

// Monotonic float -> uint transform (ascending order preserved).
__device__ __forceinline__ unsigned key_of(float v) {
    unsigned u = __float_as_uint(v);
    return u ^ ((u >> 31) ? 0xFFFFFFFFu : 0x80000000u);
}

__device__ __forceinline__ bool comes_first(float va, int ia, float vb, int ib) {
    return (va > vb) || (va == vb && ia < ib);
}

// ---------------------------------------------------------------------------
// Kernel 1: edge scores, 4 candidates per 64-lane wave. Lane l holds float4
// l of each row (4 independent 1 KB row-gathers in flight per wave). The
// ||inj|| tree is reduced once per wave; per candidate we reduce dot and
// ||cand||^2 via shfl_xor butterflies. NO global atomics here (round-3
// lesson: contended device-scope atomics serialized ~600cy/op -> +80us).
// ---------------------------------------------------------------------------
__global__ __launch_bounds__(256) void edge_score_kernel(
    const float* __restrict__ infl,
    const float* __restrict__ feats,
    const int*   __restrict__ cand,
    const float* __restrict__ inj,
    float*       __restrict__ scores,   // d_out + KSEL
    int num_cand)
{
    const int gtid = blockIdx.x * blockDim.x + threadIdx.x;
    const int wave = gtid >> 6;
    const int lane = threadIdx.x & 63;
    const int base = wave * CPW;
    if (base >= num_cand) return;

    const float4 g = *reinterpret_cast<const float4*>(inj + lane * 4);
    float ng = g.x * g.x + g.y * g.y + g.z * g.z + g.w * g.w;
    #pragma unroll
    for (int off = 32; off > 0; off >>= 1) ng += __shfl_xor(ng, off);
    const float inj_n = fmaxf(sqrtf(ng), EPS_F);

    // Issue all 4 row loads (independent -> memory-level parallelism).
    float4 f0, f1, f2, f3;
    const int n_here = num_cand - base;   // >= 1
    {
        const int r0 = cand[base];
        const int r1 = (n_here > 1) ? cand[base + 1] : r0;
        const int r2 = (n_here > 2) ? cand[base + 2] : r0;
        const int r3 = (n_here > 3) ? cand[base + 3] : r0;
        f0 = *reinterpret_cast<const float4*>(feats + (size_t)r0 * FEAT + lane * 4);
        f1 = *reinterpret_cast<const float4*>(feats + (size_t)r1 * FEAT + lane * 4);
        f2 = *reinterpret_cast<const float4*>(feats + (size_t)r2 * FEAT + lane * 4);
        f3 = *reinterpret_cast<const float4*>(feats + (size_t)r3 * FEAT + lane * 4);
    }

    float dot0 = f0.x*g.x + f0.y*g.y + f0.z*g.z + f0.w*g.w;
    float nf0  = f0.x*f0.x + f0.y*f0.y + f0.z*f0.z + f0.w*f0.w;
    float dot1 = f1.x*g.x + f1.y*g.y + f1.z*g.z + f1.w*g.w;
    float nf1  = f1.x*f1.x + f1.y*f1.y + f1.z*f1.z + f1.w*f1.w;
    float dot2 = f2.x*g.x + f2.y*g.y + f2.z*g.z + f2.w*g.w;
    float nf2  = f2.x*f2.x + f2.y*f2.y + f2.z*f2.z + f2.w*f2.w;
    float dot3 = f3.x*g.x + f3.y*g.y + f3.z*g.z + f3.w*g.w;
    float nf3  = f3.x*f3.x + f3.y*f3.y + f3.z*f3.z + f3.w*f3.w;

    // 8 independent butterfly chains -> good ILP across the 6 steps.
    #pragma unroll
    for (int off = 32; off > 0; off >>= 1) {
        dot0 += __shfl_xor(dot0, off);  nf0 += __shfl_xor(nf0, off);
        dot1 += __shfl_xor(dot1, off);  nf1 += __shfl_xor(nf1, off);
        dot2 += __shfl_xor(dot2, off);  nf2 += __shfl_xor(nf2, off);
        dot3 += __shfl_xor(dot3, off);  nf3 += __shfl_xor(nf3, off);
    }

    if (lane == 0) {
        scores[base] = infl[base] - GAMMA_F * (dot0 / (fmaxf(sqrtf(nf0), EPS_F) * inj_n));
        if (n_here > 1)
            scores[base+1] = infl[base+1] - GAMMA_F * (dot1 / (fmaxf(sqrtf(nf1), EPS_F) * inj_n));
        if (n_here > 2)
            scores[base+2] = infl[base+2] - GAMMA_F * (dot2 / (fmaxf(sqrtf(nf2), EPS_F) * inj_n));
        if (n_here > 3)
            scores[base+3] = infl[base+3] - GAMMA_F * (dot3 / (fmaxf(sqrtf(nf3), EPS_F) * inj_n));
    }
}

// ---------------------------------------------------------------------------
// Kernel 2: 13-bit histogram of score keys. LDS pre-aggregation over ~780
// elements per block, then merge nonzero buckets (<=64 global atomics per
// address across the whole grid -> no serialization cliff).
// ---------------------------------------------------------------------------
__global__ __launch_bounds__(256) void hist_kernel(
    const float* __restrict__ scores,
    unsigned*    __restrict__ hist,
    int n)
{
    __shared__ unsigned h[NBUCK];
    for (int i = threadIdx.x; i < NBUCK; i += 256) h[i] = 0;
    __syncthreads();
    for (int i = blockIdx.x * 256 + threadIdx.x; i < n; i += gridDim.x * 256)
        atomicAdd(&h[key_of(scores[i]) >> 19], 1u);
    __syncthreads();
    for (int i = threadIdx.x; i < NBUCK; i += 256)
        if (h[i]) atomicAdd(&hist[i], h[i]);
}

// ---------------------------------------------------------------------------
// Kernel 3: fused select. Each block redundantly computes threshold bucket B
// (suffix-scan of the L2-hot 32 KB histogram), grid-strides the compaction of
// survivors (bucket >= B), then the LAST block to finish (device-scope ticket,
// no dispatch-order assumption) bitonic-sorts the ~90 survivors and writes
// the exact top-64 node indices.
// ---------------------------------------------------------------------------
__global__ __launch_bounds__(256) void select_kernel(
    const float*    __restrict__ scores,
    const unsigned* __restrict__ hist,
    unsigned*       __restrict__ cnt,
    unsigned*       __restrict__ done,
    float*          __restrict__ ws_v,
    int*            __restrict__ ws_i,
    const int*      __restrict__ cand,
    float*          __restrict__ out,   // d_out[0..KSEL)
    int n)
{
    __shared__ unsigned csum[256];
    __shared__ unsigned sB;
    __shared__ int      sLast;
    __shared__ float    sv[CAP];
    __shared__ int      si[CAP];

    const int t = threadIdx.x;

    // --- 1. threshold bucket B (computed redundantly per block) ---
    {
        const int hi = NBUCK - 32 * t;     // chunk t = buckets [hi-32, hi)
        unsigned s = 0;
        for (int b = hi - 32; b < hi; ++b) s += hist[b];
        csum[t] = s;
    }
    __syncthreads();
    if (t == 0) {
        unsigned cum = 0;
        int tc = 0;
        for (; tc < 256; ++tc) {
            if (cum + csum[tc] >= KSEL) break;
            cum += csum[tc];
        }
        unsigned B = 0;
        if (tc < 256) {
            int b = NBUCK - 32 * tc - 1;
            for (int k = 0; k < 32; ++k, --b) {
                cum += hist[b];
                if (cum >= KSEL) { B = (unsigned)b; break; }
            }
        }
        sB = B;
    }
    __syncthreads();
    const unsigned B = sB;

    // --- 2. compact survivors (grid-stride) ---
    for (int i = blockIdx.x * 256 + t; i < n; i += NB2 * 256) {
        const float v = scores[i];
        if ((key_of(v) >> 19) >= B) {
            const unsigned p = atomicAdd(cnt, 1u);
            if (p < CAP) { ws_v[p] = v; ws_i[p] = i; }
        }
    }

    // --- 3. last-finished block does the final top-64 ---
    __threadfence();            // publish ws_v/ws_i before the ticket
    __syncthreads();
    if (t == 0) sLast = (atomicAdd(done, 1u) == (unsigned)(NB2 - 1));
    __syncthreads();
    if (!sLast) return;
    __threadfence();            // acquire other blocks' ws_v/ws_i writes

    const int m = (int)min(atomicAdd(cnt, 0u), (unsigned)CAP);

    if (m <= 256) {
        // bitonic sort of 256 slots: value desc, index asc (lax.top_k order)
        sv[t] = (t < m) ? ws_v[t] : -INFINITY;
        si[t] = (t < m) ? ws_i[t] : INT_MAX;
        __syncthreads();
        for (int k = 2; k <= 256; k <<= 1) {
            for (int j = k >> 1; j > 0; j >>= 1) {
                const int p = t ^ j;
                if (p > t) {
                    const float va = sv[t], vb = sv[p];
                    const int   ia = si[t], ib = si[p];
                    const bool asc = ((t & k) == 0);
                    const bool doSwap = asc ? comes_first(vb, ib, va, ia)
                                            : comes_first(va, ia, vb, ib);
                    if (doSwap) { sv[t] = vb; si[t] = ib; sv[p] = va; si[p] = ia; }
                }
                __syncthreads();
            }
        }
        if (t < KSEL) out[t] = (float)cand[si[t]];
        return;
    }

    // Fallback (never expected): serial argmax over m <= CAP survivors.
    __shared__ float wv[4];
    __shared__ int   wbi[4], wbs[4];
    for (int i = t; i < CAP; i += 256) {
        sv[i] = (i < m) ? ws_v[i] : -INFINITY;
        si[i] = (i < m) ? ws_i[i] : INT_MAX;
    }
    __syncthreads();
    for (int k = 0; k < KSEL; ++k) {
        float bv = -INFINITY; int bi = INT_MAX; int bs = 0;
        for (int i = t; i < CAP; i += 256) {
            if (comes_first(sv[i], si[i], bv, bi)) { bv = sv[i]; bi = si[i]; bs = i; }
        }
        #pragma unroll
        for (int off = 32; off > 0; off >>= 1) {
            const float ov = __shfl_xor(bv, off);
            const int   oi = __shfl_xor(bi, off);
            const int   os = __shfl_xor(bs, off);
            if (comes_first(ov, oi, bv, bi)) { bv = ov; bi = oi; bs = os; }
        }
        const int w = t >> 6;
        if ((t & 63) == 0) { wv[w] = bv; wbi[w] = bi; wbs[w] = bs; }
        __syncthreads();
        if (t == 0) {
            float fv = wv[0]; int fi = wbi[0]; int fs = wbs[0];
            #pragma unroll
            for (int j = 1; j < 4; ++j)
                if (comes_first(wv[j], wbi[j], fv, fi)) { fv = wv[j]; fi = wbi[j]; fs = wbs[j]; }
            out[k] = (float)cand[fi];
            sv[fs] = -INFINITY;
            si[fs] = INT_MAX;
        }
        __syncthreads();
    }
}

extern "C" void kernel_launch(void* const* d_in, const int* in_sizes, int n_in,
                              void* d_out, int out_size, void* d_ws, size_t ws_size,
                              hipStream_t stream) {
    const float* infl  = (const float*)d_in[0];   // [num_cand]
    const float* feats = (const float*)d_in[1];   // [num_nodes, 256]
    const int*   cand  = (const int*)d_in[2];     // [num_cand]
    const float* inj   = (const float*)d_in[3];   // [256]

    const int num_cand = in_sizes[0];

    float* out    = (float*)d_out;          // [0..64): indices-as-f32
    float* scores = (float*)d_out + KSEL;   // [64..64+num_cand): edge scores

    unsigned* ws_hist = (unsigned*)d_ws;              // NBUCK
    unsigned* ws_cnt  = ws_hist + NBUCK;              // 1
    unsigned* ws_done = ws_cnt + 1;                   // 1
    float*    ws_v    = (float*)(ws_done + 1);        // CAP
    int*      ws_i    = (int*)(ws_v + CAP);           // CAP

    // Zero histogram + counters (harness does not re-poison between replays).
    hipMemsetAsync(ws_hist, 0, (NBUCK + 2) * sizeof(unsigned), stream);

    // 1. Edge scores: 4 candidates per wave, 16 per block.
    {
        const int waves  = (num_cand + CPW - 1) / CPW;
        const int blocks = (waves + 3) / 4;
        edge_score_kernel<<<blocks, 256, 0, stream>>>(
            infl, feats, cand, inj, scores, num_cand);
    }

    // 2. Histogram of score keys (LDS pre-aggregated).
    hist_kernel<<<64, 256, 0, stream>>>(scores, ws_hist, num_cand);

    // 3. Fused threshold + compact + final top-64.
    select_kernel<<<NB2, 256, 0, stream>>>(
        scores, ws_hist, ws_cnt, ws_done, ws_v, ws_i, cand, out, num_cand);
}